// Round 5
// baseline (90056.537 us; speedup 1.0000x reference)
//
#include <hip/hip_runtime.h>

#define B_ 1024
#define T_ 256
#define V_ 90
#define H_ 256
#define NTHR 512
#define NBLK 256
#define S_ (B_*H_)

// ---------------- ws layout (float offsets) ----------------
constexpr size_t OFF_GH1C = 0;
constexpr size_t OFF_GC1C = OFF_GH1C + S_;
constexpr size_t OFF_GH1P = OFF_GC1C + S_;
constexpr size_t OFF_GC1P = OFF_GH1P + S_;
constexpr size_t OFF_LH1  = OFF_GC1P + S_;      // 2 buffers
constexpr size_t OFF_LC1  = OFF_LH1 + 2*S_;
constexpr size_t OFF_GH2C = OFF_LC1 + 2*S_;
constexpr size_t OFF_GC2C = OFF_GH2C + S_;
constexpr size_t OFF_GH2P = OFF_GC2C + S_;
constexpr size_t OFF_GC2P = OFF_GH2P + S_;
constexpr size_t OFF_LH2  = OFF_GC2P + S_;      // 2 buffers
constexpr size_t OFF_LC2  = OFF_LH2 + 2*S_;
constexpr size_t OFF_MLP1 = OFF_LC2 + 2*S_;     // 1024*512
constexpr size_t OFF_EX   = OFF_MLP1 + (size_t)B_*512;  // 2*1024*8
constexpr size_t OFF_WG1  = OFF_EX + 2*B_*8;    // [256][2048]
constexpr size_t OFF_WE1  = OFF_WG1 + 256*2048; // [8][2048]
constexpr size_t OFF_BG1  = OFF_WE1 + 8*2048;   // [2048]
constexpr size_t OFF_WL2  = OFF_BG1 + 2048;     // [512][1024]
constexpr size_t OFF_BL2  = OFF_WL2 + 512*1024; // [1024]
constexpr size_t OFF_WG2  = OFF_BL2 + 1024;     // [512][1024]
constexpr size_t OFF_BG2  = OFF_WG2 + 512*1024; // [1024]
constexpr size_t OFF_WP1  = OFF_BG2 + 1024;     // [1024][512]
constexpr size_t OFF_WEP1 = OFF_WP1 + 1024*512; // [8][512]
constexpr size_t OFF_WP2  = OFF_WEP1 + 8*512;   // [1024][512]
constexpr size_t OFF_WEP2 = OFF_WP2 + 1024*512; // [8][512]
constexpr size_t OFF_WB1  = OFF_WEP2 + 8*512;   // [512][256]
constexpr size_t OFF_WB2  = OFF_WB1 + 512*256;  // [512][256]
constexpr size_t OFF_WOUT = OFF_WB2 + 512*256;  // [256][96]
constexpr size_t OFF_BOUT = OFF_WOUT + 256*96;  // [96]
constexpr size_t OFF_BAR  = OFF_BOUT + 112;     // 8 XCD * 32 uints
constexpr size_t WS_FLOATS = OFF_BAR + 320;

struct InP {
  const int*   seq;
  const float* emb;
  const float *g1_Wih,*g1_Whh,*g1_bih,*g1_bhh;
  const float *g2_Wih,*g2_Whh,*g2_bih,*g2_bhh;
  const float *l1_Wih,*l1_Whh,*l1_bih,*l1_bhh;
  const float *l2_Wih,*l2_Whh,*l2_bih,*l2_bhh;
  const float *p1_W1,*p1_b1,*p1_W2,*p1_b2,*p1_W3,*p1_b3;
  const float *p2_W1,*p2_b1,*p2_W2,*p2_b2,*p2_W3,*p2_b3;
  const float *gfc_W,*gfc_b,*lfc_W,*lfc_b;
};

__device__ __forceinline__ float sig_(float x)  { return 1.f/(1.f+__expf(-x)); }
__device__ __forceinline__ float tanh_(float x) { return 1.f - 2.f/(__expf(2.f*x)+1.f); }

// nt (evict-first) loads for streaming weights: keep L2 for hot state.
// __builtin_nontemporal_load needs a native vector type, not HIP_vector_type.
typedef float f32x4_ __attribute__((ext_vector_type(4)));
__device__ __forceinline__ float4 ldnt4(const float* p) {
  f32x4_ v = __builtin_nontemporal_load((const f32x4_*)p);
  return make_float4(v.x, v.y, v.z, v.w);
}
__device__ __forceinline__ float ldnt1(const float* p) {
  return __builtin_nontemporal_load(p);
}

// -------- per-XCD barrier: 32 blocks, relaxed spin, L1-ONLY invalidate ------
// All data deps are intra-XCD (rows partitioned by physical XCC_ID). Producer
// stores reach the XCD's L2 (write-through L1 + vmcnt(0) drain inside
// __syncthreads). Consumers are on the same XCD, so visibility only requires
// invalidating the consumer CU's vector L1: buffer_inv sc0. Crucially this
// does NOT touch L2 (the agent-scope fence did, flushing weights+states).
__device__ __forceinline__ void gbar_x(unsigned* barx)
{
  __syncthreads();
  if (threadIdx.x == 0) {
    unsigned g = __hip_atomic_load(&barx[1], __ATOMIC_RELAXED, __HIP_MEMORY_SCOPE_AGENT);
    unsigned a = __hip_atomic_fetch_add(&barx[0], 1u, __ATOMIC_RELAXED, __HIP_MEMORY_SCOPE_AGENT);
    if (a == 31u) {
      __hip_atomic_store(&barx[0], 0u, __ATOMIC_RELAXED, __HIP_MEMORY_SCOPE_AGENT);
      __hip_atomic_fetch_add(&barx[1], 1u, __ATOMIC_RELAXED, __HIP_MEMORY_SCOPE_AGENT);
    } else {
      long cap = 0;
      while (__hip_atomic_load(&barx[1], __ATOMIC_RELAXED, __HIP_MEMORY_SCOPE_AGENT) == g
             && ++cap < 200000000L)
        __builtin_amdgcn_s_sleep(1);
    }
  }
  __syncthreads();
  asm volatile("buffer_inv sc0" ::: "memory");   // vL1 invalidate only
}

// ============ vectorized tile GEMM, depth-2 register prefetch ============
// C tile: 64 rows x CT cols. 512 threads. TC=4. TR = 64*NTX/512.
// A from up-to-4 row-major [1024][256] segments; W k-major [K][ldw], nt loads.
template<int CT, int TR, int NSEG, bool HASE, class FE>
__device__ __forceinline__ void mm_tile(
    float* sAb, float* sWb, float* sWe, float* sE,
    const float* s0, const float* s1_, const float* s2_, const float* s3_,
    const float* Wm, int ldw, int ct0,
    const float* We, int ldwe, const float* ex,
    int r0, FE fe)
{
  constexpr int NTX = CT / 4;
  constexpr int LDW = CT + 4;
  constexpr int K   = NSEG * 256;
  constexpr int NC  = K / 32;               // even (8/16/32)
  constexpr int WPT = (32*CT)/NTHR;         // 8 (CT=128) or 4 (CT=64)
  const int tid = threadIdx.x;
  const int tx = tid % NTX, ty = tid / NTX;
  const int ar = tid >> 3, ak = (tid & 7) << 2;
  const int kkw = tid >> 4, cw = (tid & 15) * WPT;

  if (HASE) {
    for (int i = tid; i < 8*CT; i += NTHR) {
      int kk = i / CT, c = i - kk*CT;
      sWe[kk*LDW + c] = ldnt1(&We[(size_t)kk*ldwe + ct0 + c]);
    }
    sE[tid] = ex[((r0 + (tid>>3))<<3) + (tid & 7)];
  }

  float acc[TR][4];
#pragma unroll
  for (int i = 0; i < TR; ++i)
#pragma unroll
    for (int j = 0; j < 4; ++j) acc[i][j] = 0.f;

  auto lda = [&](int k0) -> float4 {
    const float* S;
    if (NSEG == 1) S = s0;
    else if (NSEG == 2) S = (k0 < 256) ? s0 : s1_;
    else S = (k0 < 256) ? s0 : (k0 < 512) ? s1_ : (k0 < 768) ? s2_ : s3_;
    return *(const float4*)&S[(size_t)(r0 + ar)*H_ + (k0 & 255) + ak];
  };
  auto ldwv0 = [&](int k0) { return ldnt4(&Wm[(size_t)(k0 + kkw)*ldw + ct0 + cw]); };
  auto ldwv1 = [&](int k0) { return ldnt4(&Wm[(size_t)(k0 + kkw)*ldw + ct0 + cw + 4]); };

  auto storec = [&](int pb, const float4& pa, const float4& pw0, const float4& pw1) {
    float* a = sAb + pb*2176;
    a[(ak+0)*68 + ar] = pa.x; a[(ak+1)*68 + ar] = pa.y;
    a[(ak+2)*68 + ar] = pa.z; a[(ak+3)*68 + ar] = pa.w;
    float* w = sWb + pb*4224 + kkw*LDW + cw;
    *(float4*)w = pw0;
    if (WPT == 8) *(float4*)(w+4) = pw1;
  };

  auto compute = [&](const float* a, const float* w) {
#pragma unroll 8
    for (int kk = 0; kk < 32; ++kk) {
      float4 wv = *(const float4*)&w[kk*LDW + tx*4];
      if constexpr (TR == 4) {
        float4 av = *(const float4*)&a[kk*68 + ty*4];
        float avv[4] = {av.x, av.y, av.z, av.w};
#pragma unroll
        for (int i = 0; i < 4; ++i) {
          acc[i][0] = __builtin_fmaf(avv[i], wv.x, acc[i][0]);
          acc[i][1] = __builtin_fmaf(avv[i], wv.y, acc[i][1]);
          acc[i][2] = __builtin_fmaf(avv[i], wv.z, acc[i][2]);
          acc[i][3] = __builtin_fmaf(avv[i], wv.w, acc[i][3]);
        }
      } else {
        float2 av = *(const float2*)&a[kk*68 + ty*2];
        float avv[2] = {av.x, av.y};
#pragma unroll
        for (int i = 0; i < 2; ++i) {
          acc[i][0] = __builtin_fmaf(avv[i], wv.x, acc[i][0]);
          acc[i][1] = __builtin_fmaf(avv[i], wv.y, acc[i][1]);
          acc[i][2] = __builtin_fmaf(avv[i], wv.z, acc[i][2]);
          acc[i][3] = __builtin_fmaf(avv[i], wv.w, acc[i][3]);
        }
      }
    }
  };

  // ---- prologue: chunks 0 and 1 in flight (two STATIC register sets) ----
  float4 pa0, pw00, pw01, pa1, pw10, pw11;
  pa0 = lda(0);  pw00 = ldwv0(0);  if (WPT == 8) pw01 = ldwv1(0);
  pa1 = lda(32); pw10 = ldwv0(32); if (WPT == 8) pw11 = ldwv1(32);
  storec(0, pa0, pw00, pw01);
  __syncthreads();

  for (int c = 0; c < NC; c += 2) {
    if (c + 2 < NC) { pa0 = lda((c+2)*32); pw00 = ldwv0((c+2)*32); if (WPT == 8) pw01 = ldwv1((c+2)*32); }
    compute(sAb, sWb);                        // buffer 0 = chunk c
    storec(1, pa1, pw10, pw11);               // chunk c+1 -> buffer 1
    __syncthreads();
    if (c + 3 < NC) { pa1 = lda((c+3)*32); pw10 = ldwv0((c+3)*32); if (WPT == 8) pw11 = ldwv1((c+3)*32); }
    compute(sAb + 2176, sWb + 4224);          // buffer 1 = chunk c+1
    if (c + 2 < NC) storec(0, pa0, pw00, pw01);
    __syncthreads();
  }

  if (HASE) {
#pragma unroll
    for (int j = 0; j < 8; ++j) {
      float4 wv = *(const float4*)&sWe[j*LDW + tx*4];
#pragma unroll
      for (int i = 0; i < TR; ++i) {
        float ev = sE[(ty*TR + i)*8 + j];
        acc[i][0] = __builtin_fmaf(ev, wv.x, acc[i][0]);
        acc[i][1] = __builtin_fmaf(ev, wv.y, acc[i][1]);
        acc[i][2] = __builtin_fmaf(ev, wv.z, acc[i][2]);
        acc[i][3] = __builtin_fmaf(ev, wv.w, acc[i][3]);
      }
    }
  }
  fe(tx, ty, acc);
}

// -------- fused p-MLP2 + head + softmax + mix, 2 rows per wave --------
__device__ __forceinline__ void stage_F2(
    int rowbase,
    const float* mlp1, const float* WB, const float* b2,
    const float* W3, const float* b3,
    const float* lh, const float* lc,
    const float* ghp, const float* gcp,
    float* ghc, float* gcc)
{
  const int w = threadIdx.x >> 6, lane = threadIdx.x & 63;
  const int r0 = rowbase + w*2;
  const float* a0 = mlp1 + (size_t)r0*512;
  const float* a1 = a0 + 512;
  float m0[4] = {0.f,0.f,0.f,0.f}, m1[4] = {0.f,0.f,0.f,0.f};
  for (int k0 = 0; k0 < 512; k0 += 4) {
    float4 x0 = *(const float4*)&a0[k0];
    float4 x1 = *(const float4*)&a1[k0];
    float xv0[4] = {x0.x,x0.y,x0.z,x0.w};
    float xv1[4] = {x1.x,x1.y,x1.z,x1.w};
#pragma unroll
    for (int j = 0; j < 4; ++j) {
      float4 wv = ldnt4(&WB[(size_t)(k0+j)*256 + lane*4]);
      m0[0] = __builtin_fmaf(xv0[j], wv.x, m0[0]);
      m0[1] = __builtin_fmaf(xv0[j], wv.y, m0[1]);
      m0[2] = __builtin_fmaf(xv0[j], wv.z, m0[2]);
      m0[3] = __builtin_fmaf(xv0[j], wv.w, m0[3]);
      m1[0] = __builtin_fmaf(xv1[j], wv.x, m1[0]);
      m1[1] = __builtin_fmaf(xv1[j], wv.y, m1[1]);
      m1[2] = __builtin_fmaf(xv1[j], wv.z, m1[2]);
      m1[3] = __builtin_fmaf(xv1[j], wv.w, m1[3]);
    }
  }
  float4 b = *(const float4*)&b2[lane*4];
  float bb[4] = {b.x,b.y,b.z,b.w};
#pragma unroll
  for (int j = 0; j < 4; ++j) {
    m0[j] = fmaxf(m0[j]+bb[j], 0.f);
    m1[j] = fmaxf(m1[j]+bb[j], 0.f);
  }
  float4 w30 = *(const float4*)&W3[lane*4];
  float4 w31 = *(const float4*)&W3[256 + lane*4];
  float w0v[4] = {w30.x,w30.y,w30.z,w30.w};
  float w1v[4] = {w31.x,w31.y,w31.z,w31.w};
  float d00=0.f, d01=0.f, d10=0.f, d11=0.f;
#pragma unroll
  for (int j = 0; j < 4; ++j) {
    d00 = __builtin_fmaf(m0[j], w0v[j], d00);
    d01 = __builtin_fmaf(m0[j], w1v[j], d01);
    d10 = __builtin_fmaf(m1[j], w0v[j], d10);
    d11 = __builtin_fmaf(m1[j], w1v[j], d11);
  }
#pragma unroll
  for (int off = 32; off; off >>= 1) {
    d00 += __shfl_xor(d00, off, 64); d01 += __shfl_xor(d01, off, 64);
    d10 += __shfl_xor(d10, off, 64); d11 += __shfl_xor(d11, off, 64);
  }
  d00 += b3[0]; d01 += b3[1]; d10 += b3[0]; d11 += b3[1];
  float mxa = fmaxf(d00, d01), mxb = fmaxf(d10, d11);
  float e00 = __expf(d00-mxa), e01 = __expf(d01-mxa);
  float e10 = __expf(d10-mxb), e11 = __expf(d11-mxb);
  float ia = 1.f/(e00+e01), ib = 1.f/(e10+e11);
  float p0a = e00*ia, p1a = e01*ia;
  float p0b = e10*ib, p1b = e11*ib;
#pragma unroll
  for (int rr = 0; rr < 2; ++rr) {
    const float p0 = rr ? p0b : p0a, p1 = rr ? p1b : p1a;
    const size_t ix = (size_t)(r0+rr)*H_ + lane*4;
    float4 lv = *(const float4*)&lh[ix];
    float4 gv = *(const float4*)&ghp[ix];
    float4 o;
    o.x = p0*lv.x + p1*gv.x; o.y = p0*lv.y + p1*gv.y;
    o.z = p0*lv.z + p1*gv.z; o.w = p0*lv.w + p1*gv.w;
    *(float4*)&ghc[ix] = o;
    lv = *(const float4*)&lc[ix];
    gv = *(const float4*)&gcp[ix];
    o.x = p0*lv.x + p1*gv.x; o.y = p0*lv.y + p1*gv.y;
    o.z = p0*lv.z + p1*gv.z; o.w = p0*lv.w + p1*gv.w;
    *(float4*)&gcc[ix] = o;
  }
}

// -------- output projection, 8 rows per block (wave per row) --------
__device__ __forceinline__ void stage_OUT(
    const float* gh2c, const float* WOUT, const float* BOUT,
    float* out, int rbase, int tt)
{
  const int w = threadIdx.x >> 6, lane = threadIdx.x & 63;
  const int r = rbase + w;
  const float* arow = gh2c + (size_t)r * H_;
  float acc0 = 0.f, acc1 = 0.f;
  const bool two = lane < (V_ - 64);
  for (int k0 = 0; k0 < 256; k0 += 4) {
    float4 a4 = *(const float4*)&arow[k0];
    float av[4] = {a4.x, a4.y, a4.z, a4.w};
#pragma unroll
    for (int j = 0; j < 4; ++j) {
      const float* wr = &WOUT[(size_t)(k0+j)*96];
      acc0 = __builtin_fmaf(av[j], ldnt1(&wr[lane]), acc0);
      if (two) acc1 = __builtin_fmaf(av[j], ldnt1(&wr[64+lane]), acc1);
    }
  }
  out[((size_t)r*V_ + lane)*T_ + tt] = acc0 + BOUT[lane];
  if (two) out[((size_t)r*V_ + 64 + lane)*T_ + tt] = acc1 + BOUT[64+lane];
}

// ---------------- gate / mlp epilogues ----------------
template<int TR>
struct GateEpi {
  const float* cin; float* ho; float* co; const float* bias; int r0; int hbase;
  __device__ void operator()(int tx, int ty, float (&acc)[TR][4]) const {
    const int h = hbase + tx;
    const float b0 = bias[tx*4+0], b1 = bias[tx*4+1];
    const float b2 = bias[tx*4+2], b3 = bias[tx*4+3];
#pragma unroll
    for (int i = 0; i < TR; ++i) {
      const int r = r0 + ty*TR + i;
      const size_t ix = (size_t)r*H_ + h;
      float gi = sig_(acc[i][0]+b0), gf = sig_(acc[i][1]+b1);
      float gg = tanh_(acc[i][2]+b2), go = sig_(acc[i][3]+b3);
      float cn = gf*cin[ix] + gi*gg;
      ho[ix] = go*tanh_(cn); co[ix] = cn;
    }
  }
};

struct MlpEpi {
  float* mlp1; const float* b1; int r0; int c0;
  __device__ void operator()(int tx, int ty, float (&acc)[2][4]) const {
    const float4 b = *(const float4*)&b1[c0 + tx*4];
#pragma unroll
    for (int i = 0; i < 2; ++i) {
      const int r = r0 + ty*2 + i;
      float4 o;
      o.x = fmaxf(acc[i][0]+b.x, 0.f); o.y = fmaxf(acc[i][1]+b.y, 0.f);
      o.z = fmaxf(acc[i][2]+b.z, 0.f); o.w = fmaxf(acc[i][3]+b.w, 0.f);
      *(float4*)&mlp1[(size_t)r*512 + c0 + tx*4] = o;
    }
  }
};

// ---------------- setup: zero states/bar, gather ex0, pack weights ---------
__global__ void k_setup(InP in, float* __restrict__ ws)
{
  const size_t nthr = (size_t)gridDim.x * blockDim.x;
  const size_t t0 = (size_t)blockIdx.x * blockDim.x + threadIdx.x;

  for (size_t i = t0; i < 16*(size_t)S_; i += nthr) ws[i] = 0.f;
  for (size_t i = t0; i < 320; i += nthr) ((unsigned*)(ws + OFF_BAR))[i] = 0u;

  for (size_t i = t0; i < (size_t)B_*8; i += nthr) {
    int r = (int)(i >> 3), j = (int)(i & 7);
    ws[OFF_EX + i] = in.emb[(size_t)in.seq[(size_t)r*T_]*8 + j];
  }
  for (size_t i = t0; i < (size_t)256*2048; i += nthr) {
    int k = (int)(i >> 11), n = (int)(i & 2047);
    int cell = n >> 10, nn = n & 1023, h = nn >> 2, g = nn & 3, row = g*256 + h;
    const float* W = cell ? in.l1_Whh : in.g1_Whh;
    ws[OFF_WG1 + i] = W[(size_t)row*256 + k];
  }
  for (size_t i = t0; i < (size_t)8*2048; i += nthr) {
    int k = (int)(i >> 11), n = (int)(i & 2047);
    int cell = n >> 10, nn = n & 1023, h = nn >> 2, g = nn & 3, row = g*256 + h;
    const float* W = cell ? in.l1_Wih : in.g1_Wih;
    ws[OFF_WE1 + i] = W[(size_t)row*8 + k];
  }
  for (size_t i = t0; i < 2048; i += nthr) {
    int cell = (int)(i >> 10), nn = (int)(i & 1023), h = nn >> 2, g = nn & 3, row = g*256 + h;
    ws[OFF_BG1 + i] = cell ? (in.l1_bih[row] + in.l1_bhh[row]) : (in.g1_bih[row] + in.g1_bhh[row]);
  }
  for (size_t i = t0; i < (size_t)2*512*1024; i += nthr) {
    int cell = (int)(i / (512*1024));
    int idx = (int)(i - (size_t)cell*512*1024);
    int k = idx >> 10, n = idx & 1023, h = n >> 2, g = n & 3, row = g*256 + h;
    const float* Wih = cell ? in.l2_Wih : in.g2_Wih;
    const float* Whh = cell ? in.l2_Whh : in.g2_Whh;
    float v = (k < 256) ? Wih[(size_t)row*256 + k] : Whh[(size_t)row*256 + (k-256)];
    ws[(cell ? OFF_WL2 : OFF_WG2) + idx] = v;
  }
  for (size_t i = t0; i < 2048; i += nthr) {
    int cell = (int)(i >> 10), n = (int)(i & 1023), h = n >> 2, g = n & 3, row = g*256 + h;
    float v = cell ? (in.l2_bih[row] + in.l2_bhh[row]) : (in.g2_bih[row] + in.g2_bhh[row]);
    ws[(cell ? OFF_BL2 : OFF_BG2) + n] = v;
  }
  for (size_t i = t0; i < (size_t)2*1024*512; i += nthr) {
    int which = (int)(i / (1024*512));
    int idx = (int)(i - (size_t)which*1024*512);
    int k = idx >> 9, n = idx & 511;
    const float* W = which ? in.p2_W1 : in.p1_W1;
    ws[(which ? OFF_WP2 : OFF_WP1) + idx] = W[(size_t)n*1032 + 8 + k];
  }
  for (size_t i = t0; i < (size_t)2*8*512; i += nthr) {
    int which = (int)(i / (8*512));
    int idx = (int)(i - (size_t)which*8*512);
    int k = idx >> 9, n = idx & 511;
    const float* W = which ? in.p2_W1 : in.p1_W1;
    ws[(which ? OFF_WEP2 : OFF_WEP1) + idx] = W[(size_t)n*1032 + k];
  }
  for (size_t i = t0; i < (size_t)2*512*256; i += nthr) {
    int which = (int)(i / (512*256));
    int idx = (int)(i - (size_t)which*512*256);
    int k = idx >> 8, n = idx & 255;
    const float* W = which ? in.p2_W2 : in.p1_W2;
    ws[(which ? OFF_WB2 : OFF_WB1) + idx] = W[(size_t)n*512 + k];
  }
  for (size_t i = t0; i < (size_t)256*96; i += nthr) {
    int k = (int)(i / 96), c = (int)(i - (size_t)k*96);
    float v = 0.f;
    if (c < V_) v = 0.5f*(in.gfc_W[(size_t)c*256 + k] + in.lfc_W[(size_t)c*256 + k]);
    ws[OFF_WOUT + i] = v;
  }
  for (size_t i = t0; i < 96; i += nthr)
    ws[OFF_BOUT + i] = (i < V_) ? 0.5f*(in.gfc_b[i] + in.lfc_b[i]) : 0.f;
}

// ---------------- main persistent kernel (XCD-local) ----------------
__global__ __launch_bounds__(NTHR) void k_main(InP in, float* ws, float* __restrict__ out)
{
  __shared__ __attribute__((aligned(16))) float sA[2*2176];
  __shared__ __attribute__((aligned(16))) float sW[2*4224];
  __shared__ __attribute__((aligned(16))) float sWe[8*132];
  __shared__ __attribute__((aligned(16))) float sE[512];
  // + 28KB dynamic LDS (unused) pushes total >80KB -> exactly 1 block/CU,
  // so 256 blocks <-> 256 CUs and each XCD hosts exactly 32 blocks.

  float* GH1C = ws + OFF_GH1C;  float* GC1C = ws + OFF_GC1C;
  float* GH1P = ws + OFF_GH1P;  float* GC1P = ws + OFF_GC1P;
  float* LH1  = ws + OFF_LH1;   float* LC1  = ws + OFF_LC1;
  float* GH2C = ws + OFF_GH2C;  float* GC2C = ws + OFF_GC2C;
  float* GH2P = ws + OFF_GH2P;  float* GC2P = ws + OFF_GC2P;
  float* LH2  = ws + OFF_LH2;   float* LC2  = ws + OFF_LC2;
  float* MLP1 = ws + OFF_MLP1;  float* EXB  = ws + OFF_EX;
  const float* WG1 = ws + OFF_WG1;  const float* WE1 = ws + OFF_WE1;  const float* BG1 = ws + OFF_BG1;
  const float* WL2 = ws + OFF_WL2;  const float* BL2 = ws + OFF_BL2;
  const float* WG2 = ws + OFF_WG2;  const float* BG2 = ws + OFF_BG2;
  const float* WP1 = ws + OFF_WP1;  const float* WEP1 = ws + OFF_WEP1;
  const float* WP2 = ws + OFF_WP2;  const float* WEP2 = ws + OFF_WEP2;
  const float* WB1 = ws + OFF_WB1;  const float* WB2 = ws + OFF_WB2;
  const float* WOUT = ws + OFF_WOUT; const float* BOUT = ws + OFF_BOUT;

  // ---- physical XCD id + slot within XCD ----
  unsigned xcc;
  asm volatile("s_getreg_b32 %0, hwreg(HW_REG_XCC_ID)" : "=s"(xcc));
  xcc &= 7u;
  unsigned* barx = ((unsigned*)(ws + OFF_BAR)) + xcc*32;
  __shared__ unsigned s_slot;
  if (threadIdx.x == 0)
    s_slot = __hip_atomic_fetch_add(&barx[2], 1u, __ATOMIC_RELAXED, __HIP_MEMORY_SCOPE_AGENT);
  __syncthreads();
  const int slot  = (int)(s_slot & 31u);
  const int rows0 = (int)xcc * 128;

  for (int t = 0; t < T_; ++t) {
    const int sel = t & 1;
    const float* ex = EXB + sel*(B_*8);
    float* lh1o = LH1 + sel*S_;      float* lh1n = LH1 + (sel^1)*S_;
    float* lc1o = LC1 + sel*S_;      float* lc1n = LC1 + (sel^1)*S_;
    float* lh2o = LH2 + sel*S_;      float* lh2n = LH2 + (sel^1)*S_;
    float* lc2o = LC2 + sel*S_;      float* lc2n = LC2 + (sel^1)*S_;

    // ===== S1: layer-1 gates (g1 | l1): 32 slots, tile 64x128 =====
    {
      const int rt = slot & 1, ct = slot >> 1;      // ct in [0,16)
      const int r0 = rows0 + rt*64, ct0 = ct*128;
      const int cell = ct >> 3;
      GateEpi<4> epi{ cell ? lc1o : GC1C,
                      cell ? lh1n : GH1P,
                      cell ? lc1n : GC1P,
                      BG1 + ct0, r0, (ct0 & 1023) >> 2 };
      mm_tile<128,4,1,true>(sA, sW, sWe, sE,
                            cell ? lh1o : GH1C, nullptr, nullptr, nullptr,
                            WG1, 2048, ct0, WE1, 2048, ex, r0, epi);
    }
    gbar_x(barx);

    // ===== S2: p1-MLP1 (slots 0-15) || l2 gates (slots 16-31) =====
    if (slot < 16) {
      const int rt = slot & 1, ct = slot >> 1;      // ct in [0,8)
      const int r0 = rows0 + rt*64, c0 = ct*64;
      MlpEpi epi{ MLP1, in.p1_b1, r0, c0 };
      mm_tile<64,2,4,true>(sA, sW, sWe, sE,
                           GH1P, GC1P, lh1n, lc1n,
                           WP1, 512, c0, WEP1, 512, ex, r0, epi);
    } else {
      const int s2 = slot - 16;
      const int rt = s2 & 1, ct = s2 >> 1;          // ct in [0,8)
      const int r0 = rows0 + rt*64, ct0 = ct*128;
      GateEpi<4> epi{ lc2o, lh2n, lc2n, BL2 + ct0, r0, ct0 >> 2 };
      mm_tile<128,4,2,false>(sA, sW, sWe, sE,
                             lh1n, lh2o, nullptr, nullptr,
                             WL2, 1024, ct0, nullptr, 0, nullptr, r0, epi);
    }
    gbar_x(barx);

    // ===== S3: p1 finish + mix1 (slots 0-7) || ex(t+1) (slots 8-9) =====
    if (slot < 8) {
      stage_F2(rows0 + slot*16, MLP1, WB1, in.p1_b2, in.p1_W3, in.p1_b3,
               lh1n, lc1n, GH1P, GC1P, GH1C, GC1C);
    } else if (slot < 10 && t < T_-1) {
      const int rb = rows0 + (slot-8)*64;
      const int r = rb + (threadIdx.x >> 3), j = threadIdx.x & 7;
      EXB[((t+1)&1)*(B_*8) + r*8 + j] = in.emb[(size_t)in.seq[(size_t)r*T_ + t + 1]*8 + j];
    }
    gbar_x(barx);

    // ===== S4: g2 gates: 32 slots, tile 64x64 =====
    {
      const int rt = slot & 1, ct = slot >> 1;      // ct in [0,16)
      const int r0 = rows0 + rt*64, ct0 = ct*64;
      GateEpi<2> epi{ GC2C, GH2P, GC2P, BG2 + ct0, r0, ct0 >> 2 };
      mm_tile<64,2,2,false>(sA, sW, sWe, sE,
                            GH1C, GH2C, nullptr, nullptr,
                            WG2, 1024, ct0, nullptr, 0, nullptr, r0, epi);
    }
    gbar_x(barx);

    // ===== S5: p2-MLP1 (slots 0-15) || out(t-1) (slots 16-31) =====
    if (slot < 16) {
      const int rt = slot & 1, ct = slot >> 1;
      const int r0 = rows0 + rt*64, c0 = ct*64;
      MlpEpi epi{ MLP1, in.p2_b1, r0, c0 };
      mm_tile<64,2,4,true>(sA, sW, sWe, sE,
                           GH2P, GC2P, lh2n, lc2n,
                           WP2, 512, c0, WEP2, 512, ex, r0, epi);
    } else if (t > 0) {
      stage_OUT(GH2C, WOUT, BOUT, out, rows0 + (slot-16)*8, t-1);
    }
    gbar_x(barx);

    // ===== S6: p2 finish + mix2 (slots 0-7) =====
    if (slot < 8) {
      stage_F2(rows0 + slot*16, MLP1, WB2, in.p2_b2, in.p2_W3, in.p2_b3,
               lh2n, lc2n, GH2P, GC2P, GH2C, GC2C);
    }
    gbar_x(barx);
  }

  // final output column t = 255
  if (slot >= 16) stage_OUT(GH2C, WOUT, BOUT, out, rows0 + (slot-16)*8, 255);
}

// ---------------- host ----------------
extern "C" void kernel_launch(void* const* d_in, const int* in_sizes, int n_in,
                              void* d_out, int out_size, void* d_ws, size_t ws_size,
                              hipStream_t stream)
{
  if (ws_size < WS_FLOATS * sizeof(float)) return;

  InP in;
  in.seq    = (const int*)  d_in[0];
  in.emb    = (const float*)d_in[1];
  in.g1_Wih = (const float*)d_in[2];  in.g1_Whh = (const float*)d_in[3];
  in.g1_bih = (const float*)d_in[4];  in.g1_bhh = (const float*)d_in[5];
  in.g2_Wih = (const float*)d_in[6];  in.g2_Whh = (const float*)d_in[7];
  in.g2_bih = (const float*)d_in[8];  in.g2_bhh = (const float*)d_in[9];
  in.l1_Wih = (const float*)d_in[10]; in.l1_Whh = (const float*)d_in[11];
  in.l1_bih = (const float*)d_in[12]; in.l1_bhh = (const float*)d_in[13];
  in.l2_Wih = (const float*)d_in[14]; in.l2_Whh = (const float*)d_in[15];
  in.l2_bih = (const float*)d_in[16]; in.l2_bhh = (const float*)d_in[17];
  in.p1_W1  = (const float*)d_in[18]; in.p1_b1  = (const float*)d_in[19];
  in.p1_W2  = (const float*)d_in[20]; in.p1_b2  = (const float*)d_in[21];
  in.p1_W3  = (const float*)d_in[22]; in.p1_b3  = (const float*)d_in[23];
  in.p2_W1  = (const float*)d_in[24]; in.p2_b1  = (const float*)d_in[25];
  in.p2_W2  = (const float*)d_in[26]; in.p2_b2  = (const float*)d_in[27];
  in.p2_W3  = (const float*)d_in[28]; in.p2_b3  = (const float*)d_in[29];
  in.gfc_W  = (const float*)d_in[30]; in.gfc_b  = (const float*)d_in[31];
  in.lfc_W  = (const float*)d_in[32]; in.lfc_b  = (const float*)d_in[33];

  float* ws  = (float*)d_ws;
  float* out = (float*)d_out;

  k_setup<<<256, 256, 0, stream>>>(in, ws);
  k_main <<<NBLK, NTHR, 28672, stream>>>(in, ws, out);   // 28KB dynamic LDS: occupancy pin
}

// Round 7
// 64143.402 us; speedup vs baseline: 1.4040x; 1.4040x over previous
//
#include <hip/hip_runtime.h>

#define B_ 1024
#define T_ 256
#define V_ 90
#define H_ 256
#define NTHR 512
#define NBLK 256
#define S_ (B_*H_)

// ---------------- ws layout (float offsets) ----------------
constexpr size_t OFF_GH1C = 0;
constexpr size_t OFF_GC1C = OFF_GH1C + S_;
constexpr size_t OFF_GH1P = OFF_GC1C + S_;
constexpr size_t OFF_GC1P = OFF_GH1P + S_;
constexpr size_t OFF_LH1  = OFF_GC1P + S_;      // 2 buffers
constexpr size_t OFF_LC1  = OFF_LH1 + 2*S_;
constexpr size_t OFF_GH2C = OFF_LC1 + 2*S_;
constexpr size_t OFF_GC2C = OFF_GH2C + S_;
constexpr size_t OFF_GH2P = OFF_GC2C + S_;
constexpr size_t OFF_GC2P = OFF_GH2P + S_;
constexpr size_t OFF_LH2  = OFF_GC2P + S_;      // 2 buffers
constexpr size_t OFF_LC2  = OFF_LH2 + 2*S_;
constexpr size_t OFF_MLP1 = OFF_LC2 + 2*S_;     // 1024*512
constexpr size_t OFF_EX   = OFF_MLP1 + (size_t)B_*512;  // 2*1024*8
constexpr size_t OFF_WG1  = OFF_EX + 2*B_*8;    // [256][2048]
constexpr size_t OFF_WE1  = OFF_WG1 + 256*2048; // [8][2048]
constexpr size_t OFF_BG1  = OFF_WE1 + 8*2048;   // [2048]
constexpr size_t OFF_WL2  = OFF_BG1 + 2048;     // [512][1024]
constexpr size_t OFF_BL2  = OFF_WL2 + 512*1024; // [1024]
constexpr size_t OFF_WG2  = OFF_BL2 + 1024;     // [512][1024]
constexpr size_t OFF_BG2  = OFF_WG2 + 512*1024; // [1024]
constexpr size_t OFF_WP1  = OFF_BG2 + 1024;     // [1024][512]
constexpr size_t OFF_WEP1 = OFF_WP1 + 1024*512; // [8][512]
constexpr size_t OFF_WP2  = OFF_WEP1 + 8*512;   // [1024][512]
constexpr size_t OFF_WEP2 = OFF_WP2 + 1024*512; // [8][512]
constexpr size_t OFF_WB1  = OFF_WEP2 + 8*512;   // [512][256]
constexpr size_t OFF_WB2  = OFF_WB1 + 512*256;  // [512][256]
constexpr size_t OFF_WOUT = OFF_WB2 + 512*256;  // [256][96]
constexpr size_t OFF_BOUT = OFF_WOUT + 256*96;  // [96]
constexpr size_t OFF_BAR  = OFF_BOUT + 112;     // 8 XCD * 1024 uints
constexpr size_t WS_FLOATS = OFF_BAR + 8192;

struct InP {
  const int*   seq;
  const float* emb;
  const float *g1_Wih,*g1_Whh,*g1_bih,*g1_bhh;
  const float *g2_Wih,*g2_Whh,*g2_bih,*g2_bhh;
  const float *l1_Wih,*l1_Whh,*l1_bih,*l1_bhh;
  const float *l2_Wih,*l2_Whh,*l2_bih,*l2_bhh;
  const float *p1_W1,*p1_b1,*p1_W2,*p1_b2,*p1_W3,*p1_b3;
  const float *p2_W1,*p2_b1,*p2_W2,*p2_b2,*p2_W3,*p2_b3;
  const float *gfc_W,*gfc_b,*lfc_W,*lfc_b;
};

__device__ __forceinline__ float sig_(float x)  { return 1.f/(1.f+__expf(-x)); }
__device__ __forceinline__ float tanh_(float x) { return 1.f - 2.f/(__expf(2.f*x)+1.f); }

// ---- AGENT-scope (sc1) flag ops: bypass L1 (and L2) so remote updates are
// observed. R6's sc0 (= workgroup scope) was served by the spinner's own L1
// and livelocked. R5 proved sc1 loads see cross-CU updates on this chip. ----
__device__ __forceinline__ unsigned ld_flag(const unsigned* p) {
  unsigned v;
  asm volatile("global_load_dword %0, %1, off sc1\n\ts_waitcnt vmcnt(0)"
               : "=v"(v) : "v"(p) : "memory");
  return v;
}
__device__ __forceinline__ void st_flag(unsigned* p, unsigned v) {
  asm volatile("global_store_dword %0, %1, off sc1\n\ts_waitcnt vmcnt(0)"
               :: "v"(p), "v"(v) : "memory");
}

// -------- per-XCD barrier: per-slot arrival flags (64B apart), NO RMW --------
// arrival: slot k stores epoch into arr[k*16] (own cache line -> parallel).
// leader (slot 0): 32 lanes poll the 32 arrival words in one vector load per
// iteration; then lane 0 stores epoch to go. others poll go. ~5us total vs
// ~45us for the serialized single-line RMW counter barrier.
__device__ __forceinline__ void gbar_x(unsigned* arr, unsigned* go, int slot, unsigned ep)
{
  __syncthreads();                       // waves drain vmcnt(0) -> data in L2
  if (threadIdx.x < 64) {
    if (threadIdx.x == 0) st_flag(&arr[slot*16], ep);
    if (slot == 0) {
      if (threadIdx.x < 32) {
        int cap = 0;
        for (;;) {
          unsigned v = ld_flag(&arr[threadIdx.x*16]);
          if (v >= ep) break;
          __builtin_amdgcn_s_sleep(2);
          if (++cap > 65536) break;
        }
      }
      if (threadIdx.x == 0) st_flag(go, ep);  // after reconvergence of the poll
    } else if (threadIdx.x == 0) {
      int cap = 0;
      for (;;) {
        unsigned v = ld_flag(go);
        if (v >= ep) break;
        __builtin_amdgcn_s_sleep(2);
        if (++cap > 65536) break;
      }
    }
  }
  __syncthreads();
  asm volatile("buffer_inv sc0" ::: "memory");   // vL1 invalidate only
}

// ============ vectorized tile GEMM, depth-2 register prefetch ============
// C tile: 64 rows x CT cols. 512 threads. TC=4. TR = 64*NTX/512.
// A from up-to-4 row-major [1024][256] segments; W k-major [K][ldw].
template<int CT, int TR, int NSEG, bool HASE, class FE>
__device__ __forceinline__ void mm_tile(
    float* sAb, float* sWb, float* sWe, float* sE,
    const float* s0, const float* s1_, const float* s2_, const float* s3_,
    const float* Wm, int ldw, int ct0,
    const float* We, int ldwe, const float* ex,
    int r0, FE fe)
{
  constexpr int NTX = CT / 4;
  constexpr int LDW = CT + 4;
  constexpr int K   = NSEG * 256;
  constexpr int NC  = K / 32;               // even (8/16/32)
  constexpr int WPT = (32*CT)/NTHR;         // 8 (CT=128) or 4 (CT=64)
  const int tid = threadIdx.x;
  const int tx = tid % NTX, ty = tid / NTX;
  const int ar = tid >> 3, ak = (tid & 7) << 2;
  const int kkw = tid >> 4, cw = (tid & 15) * WPT;

  if (HASE) {
    for (int i = tid; i < 8*CT; i += NTHR) {
      int kk = i / CT, c = i - kk*CT;
      sWe[kk*LDW + c] = We[(size_t)kk*ldwe + ct0 + c];
    }
    sE[tid] = ex[((r0 + (tid>>3))<<3) + (tid & 7)];
  }

  float acc[TR][4];
#pragma unroll
  for (int i = 0; i < TR; ++i)
#pragma unroll
    for (int j = 0; j < 4; ++j) acc[i][j] = 0.f;

  auto lda = [&](int k0) -> float4 {
    const float* S;
    if (NSEG == 1) S = s0;
    else if (NSEG == 2) S = (k0 < 256) ? s0 : s1_;
    else S = (k0 < 256) ? s0 : (k0 < 512) ? s1_ : (k0 < 768) ? s2_ : s3_;
    return *(const float4*)&S[(size_t)(r0 + ar)*H_ + (k0 & 255) + ak];
  };
  auto ldwv0 = [&](int k0) { return *(const float4*)&Wm[(size_t)(k0 + kkw)*ldw + ct0 + cw]; };
  auto ldwv1 = [&](int k0) { return *(const float4*)&Wm[(size_t)(k0 + kkw)*ldw + ct0 + cw + 4]; };

  auto storec = [&](int pb, const float4& pa, const float4& pw0, const float4& pw1) {
    float* a = sAb + pb*2176;
    a[(ak+0)*68 + ar] = pa.x; a[(ak+1)*68 + ar] = pa.y;
    a[(ak+2)*68 + ar] = pa.z; a[(ak+3)*68 + ar] = pa.w;
    float* w = sWb + pb*4224 + kkw*LDW + cw;
    *(float4*)w = pw0;
    if (WPT == 8) *(float4*)(w+4) = pw1;
  };

  auto compute = [&](const float* a, const float* w) {
#pragma unroll 8
    for (int kk = 0; kk < 32; ++kk) {
      float4 wv = *(const float4*)&w[kk*LDW + tx*4];
      if constexpr (TR == 4) {
        float4 av = *(const float4*)&a[kk*68 + ty*4];
        float avv[4] = {av.x, av.y, av.z, av.w};
#pragma unroll
        for (int i = 0; i < 4; ++i) {
          acc[i][0] = __builtin_fmaf(avv[i], wv.x, acc[i][0]);
          acc[i][1] = __builtin_fmaf(avv[i], wv.y, acc[i][1]);
          acc[i][2] = __builtin_fmaf(avv[i], wv.z, acc[i][2]);
          acc[i][3] = __builtin_fmaf(avv[i], wv.w, acc[i][3]);
        }
      } else {
        float2 av = *(const float2*)&a[kk*68 + ty*2];
        float avv[2] = {av.x, av.y};
#pragma unroll
        for (int i = 0; i < 2; ++i) {
          acc[i][0] = __builtin_fmaf(avv[i], wv.x, acc[i][0]);
          acc[i][1] = __builtin_fmaf(avv[i], wv.y, acc[i][1]);
          acc[i][2] = __builtin_fmaf(avv[i], wv.z, acc[i][2]);
          acc[i][3] = __builtin_fmaf(avv[i], wv.w, acc[i][3]);
        }
      }
    }
  };

  // ---- prologue: chunks 0 and 1 in flight (two STATIC register sets) ----
  float4 pa0, pw00, pw01, pa1, pw10, pw11;
  pa0 = lda(0);  pw00 = ldwv0(0);  if (WPT == 8) pw01 = ldwv1(0);
  pa1 = lda(32); pw10 = ldwv0(32); if (WPT == 8) pw11 = ldwv1(32);
  storec(0, pa0, pw00, pw01);
  __syncthreads();

  for (int c = 0; c < NC; c += 2) {
    if (c + 2 < NC) { pa0 = lda((c+2)*32); pw00 = ldwv0((c+2)*32); if (WPT == 8) pw01 = ldwv1((c+2)*32); }
    compute(sAb, sWb);                        // buffer 0 = chunk c
    storec(1, pa1, pw10, pw11);               // chunk c+1 -> buffer 1
    __syncthreads();
    if (c + 3 < NC) { pa1 = lda((c+3)*32); pw10 = ldwv0((c+3)*32); if (WPT == 8) pw11 = ldwv1((c+3)*32); }
    compute(sAb + 2176, sWb + 4224);          // buffer 1 = chunk c+1
    if (c + 2 < NC) storec(0, pa0, pw00, pw01);
    __syncthreads();
  }

  if (HASE) {
#pragma unroll
    for (int j = 0; j < 8; ++j) {
      float4 wv = *(const float4*)&sWe[j*LDW + tx*4];
#pragma unroll
      for (int i = 0; i < TR; ++i) {
        float ev = sE[(ty*TR + i)*8 + j];
        acc[i][0] = __builtin_fmaf(ev, wv.x, acc[i][0]);
        acc[i][1] = __builtin_fmaf(ev, wv.y, acc[i][1]);
        acc[i][2] = __builtin_fmaf(ev, wv.z, acc[i][2]);
        acc[i][3] = __builtin_fmaf(ev, wv.w, acc[i][3]);
      }
    }
  }
  fe(tx, ty, acc);
}

// -------- fused p-MLP2 + head + softmax + mix, 2 rows per wave --------
__device__ __forceinline__ void stage_F2(
    int rowbase,
    const float* mlp1, const float* WB, const float* b2,
    const float* W3, const float* b3,
    const float* lh, const float* lc,
    const float* ghp, const float* gcp,
    float* ghc, float* gcc)
{
  const int w = threadIdx.x >> 6, lane = threadIdx.x & 63;
  const int r0 = rowbase + w*2;
  const float* a0 = mlp1 + (size_t)r0*512;
  const float* a1 = a0 + 512;
  float m0[4] = {0.f,0.f,0.f,0.f}, m1[4] = {0.f,0.f,0.f,0.f};
  for (int k0 = 0; k0 < 512; k0 += 4) {
    float4 x0 = *(const float4*)&a0[k0];
    float4 x1 = *(const float4*)&a1[k0];
    float xv0[4] = {x0.x,x0.y,x0.z,x0.w};
    float xv1[4] = {x1.x,x1.y,x1.z,x1.w};
#pragma unroll
    for (int j = 0; j < 4; ++j) {
      float4 wv = *(const float4*)&WB[(size_t)(k0+j)*256 + lane*4];
      m0[0] = __builtin_fmaf(xv0[j], wv.x, m0[0]);
      m0[1] = __builtin_fmaf(xv0[j], wv.y, m0[1]);
      m0[2] = __builtin_fmaf(xv0[j], wv.z, m0[2]);
      m0[3] = __builtin_fmaf(xv0[j], wv.w, m0[3]);
      m1[0] = __builtin_fmaf(xv1[j], wv.x, m1[0]);
      m1[1] = __builtin_fmaf(xv1[j], wv.y, m1[1]);
      m1[2] = __builtin_fmaf(xv1[j], wv.z, m1[2]);
      m1[3] = __builtin_fmaf(xv1[j], wv.w, m1[3]);
    }
  }
  float4 b = *(const float4*)&b2[lane*4];
  float bb[4] = {b.x,b.y,b.z,b.w};
#pragma unroll
  for (int j = 0; j < 4; ++j) {
    m0[j] = fmaxf(m0[j]+bb[j], 0.f);
    m1[j] = fmaxf(m1[j]+bb[j], 0.f);
  }
  float4 w30 = *(const float4*)&W3[lane*4];
  float4 w31 = *(const float4*)&W3[256 + lane*4];
  float w0v[4] = {w30.x,w30.y,w30.z,w30.w};
  float w1v[4] = {w31.x,w31.y,w31.z,w31.w};
  float d00=0.f, d01=0.f, d10=0.f, d11=0.f;
#pragma unroll
  for (int j = 0; j < 4; ++j) {
    d00 = __builtin_fmaf(m0[j], w0v[j], d00);
    d01 = __builtin_fmaf(m0[j], w1v[j], d01);
    d10 = __builtin_fmaf(m1[j], w0v[j], d10);
    d11 = __builtin_fmaf(m1[j], w1v[j], d11);
  }
#pragma unroll
  for (int off = 32; off; off >>= 1) {
    d00 += __shfl_xor(d00, off, 64); d01 += __shfl_xor(d01, off, 64);
    d10 += __shfl_xor(d10, off, 64); d11 += __shfl_xor(d11, off, 64);
  }
  d00 += b3[0]; d01 += b3[1]; d10 += b3[0]; d11 += b3[1];
  float mxa = fmaxf(d00, d01), mxb = fmaxf(d10, d11);
  float e00 = __expf(d00-mxa), e01 = __expf(d01-mxa);
  float e10 = __expf(d10-mxb), e11 = __expf(d11-mxb);
  float ia = 1.f/(e00+e01), ib = 1.f/(e10+e11);
  float p0a = e00*ia, p1a = e01*ia;
  float p0b = e10*ib, p1b = e11*ib;
#pragma unroll
  for (int rr = 0; rr < 2; ++rr) {
    const float p0 = rr ? p0b : p0a, p1 = rr ? p1b : p1a;
    const size_t ix = (size_t)(r0+rr)*H_ + lane*4;
    float4 lv = *(const float4*)&lh[ix];
    float4 gv = *(const float4*)&ghp[ix];
    float4 o;
    o.x = p0*lv.x + p1*gv.x; o.y = p0*lv.y + p1*gv.y;
    o.z = p0*lv.z + p1*gv.z; o.w = p0*lv.w + p1*gv.w;
    *(float4*)&ghc[ix] = o;
    lv = *(const float4*)&lc[ix];
    gv = *(const float4*)&gcp[ix];
    o.x = p0*lv.x + p1*gv.x; o.y = p0*lv.y + p1*gv.y;
    o.z = p0*lv.z + p1*gv.z; o.w = p0*lv.w + p1*gv.w;
    *(float4*)&gcc[ix] = o;
  }
}

// -------- output projection, 8 rows per block (wave per row) --------
__device__ __forceinline__ void stage_OUT(
    const float* gh2c, const float* WOUT, const float* BOUT,
    float* out, int rbase, int tt)
{
  const int w = threadIdx.x >> 6, lane = threadIdx.x & 63;
  const int r = rbase + w;
  const float* arow = gh2c + (size_t)r * H_;
  float acc0 = 0.f, acc1 = 0.f;
  const bool two = lane < (V_ - 64);
  for (int k0 = 0; k0 < 256; k0 += 4) {
    float4 a4 = *(const float4*)&arow[k0];
    float av[4] = {a4.x, a4.y, a4.z, a4.w};
#pragma unroll
    for (int j = 0; j < 4; ++j) {
      const float* wr = &WOUT[(size_t)(k0+j)*96];
      acc0 = __builtin_fmaf(av[j], wr[lane], acc0);
      if (two) acc1 = __builtin_fmaf(av[j], wr[64+lane], acc1);
    }
  }
  out[((size_t)r*V_ + lane)*T_ + tt] = acc0 + BOUT[lane];
  if (two) out[((size_t)r*V_ + 64 + lane)*T_ + tt] = acc1 + BOUT[64+lane];
}

// ---------------- gate / mlp epilogues ----------------
template<int TR>
struct GateEpi {
  const float* cin; float* ho; float* co; const float* bias; int r0; int hbase;
  __device__ void operator()(int tx, int ty, float (&acc)[TR][4]) const {
    const int h = hbase + tx;
    const float b0 = bias[tx*4+0], b1 = bias[tx*4+1];
    const float b2 = bias[tx*4+2], b3 = bias[tx*4+3];
#pragma unroll
    for (int i = 0; i < TR; ++i) {
      const int r = r0 + ty*TR + i;
      const size_t ix = (size_t)r*H_ + h;
      float gi = sig_(acc[i][0]+b0), gf = sig_(acc[i][1]+b1);
      float gg = tanh_(acc[i][2]+b2), go = sig_(acc[i][3]+b3);
      float cn = gf*cin[ix] + gi*gg;
      ho[ix] = go*tanh_(cn); co[ix] = cn;
    }
  }
};

struct MlpEpi {
  float* mlp1; const float* b1; int r0; int c0;
  __device__ void operator()(int tx, int ty, float (&acc)[2][4]) const {
    const float4 b = *(const float4*)&b1[c0 + tx*4];
#pragma unroll
    for (int i = 0; i < 2; ++i) {
      const int r = r0 + ty*2 + i;
      float4 o;
      o.x = fmaxf(acc[i][0]+b.x, 0.f); o.y = fmaxf(acc[i][1]+b.y, 0.f);
      o.z = fmaxf(acc[i][2]+b.z, 0.f); o.w = fmaxf(acc[i][3]+b.w, 0.f);
      *(float4*)&mlp1[(size_t)r*512 + c0 + tx*4] = o;
    }
  }
};

// ---------------- setup: zero states/bar, gather ex0, pack weights ---------
__global__ void k_setup(InP in, float* __restrict__ ws)
{
  const size_t nthr = (size_t)gridDim.x * blockDim.x;
  const size_t t0 = (size_t)blockIdx.x * blockDim.x + threadIdx.x;

  for (size_t i = t0; i < 16*(size_t)S_; i += nthr) ws[i] = 0.f;
  for (size_t i = t0; i < 8192; i += nthr) ((unsigned*)(ws + OFF_BAR))[i] = 0u;

  for (size_t i = t0; i < (size_t)B_*8; i += nthr) {
    int r = (int)(i >> 3), j = (int)(i & 7);
    ws[OFF_EX + i] = in.emb[(size_t)in.seq[(size_t)r*T_]*8 + j];
  }
  for (size_t i = t0; i < (size_t)256*2048; i += nthr) {
    int k = (int)(i >> 11), n = (int)(i & 2047);
    int cell = n >> 10, nn = n & 1023, h = nn >> 2, g = nn & 3, row = g*256 + h;
    const float* W = cell ? in.l1_Whh : in.g1_Whh;
    ws[OFF_WG1 + i] = W[(size_t)row*256 + k];
  }
  for (size_t i = t0; i < (size_t)8*2048; i += nthr) {
    int k = (int)(i >> 11), n = (int)(i & 2047);
    int cell = n >> 10, nn = n & 1023, h = nn >> 2, g = nn & 3, row = g*256 + h;
    const float* W = cell ? in.l1_Wih : in.g1_Wih;
    ws[OFF_WE1 + i] = W[(size_t)row*8 + k];
  }
  for (size_t i = t0; i < 2048; i += nthr) {
    int cell = (int)(i >> 10), nn = (int)(i & 1023), h = nn >> 2, g = nn & 3, row = g*256 + h;
    ws[OFF_BG1 + i] = cell ? (in.l1_bih[row] + in.l1_bhh[row]) : (in.g1_bih[row] + in.g1_bhh[row]);
  }
  for (size_t i = t0; i < (size_t)2*512*1024; i += nthr) {
    int cell = (int)(i / (512*1024));
    int idx = (int)(i - (size_t)cell*512*1024);
    int k = idx >> 10, n = idx & 1023, h = n >> 2, g = n & 3, row = g*256 + h;
    const float* Wih = cell ? in.l2_Wih : in.g2_Wih;
    const float* Whh = cell ? in.l2_Whh : in.g2_Whh;
    float v = (k < 256) ? Wih[(size_t)row*256 + k] : Whh[(size_t)row*256 + (k-256)];
    ws[(cell ? OFF_WL2 : OFF_WG2) + idx] = v;
  }
  for (size_t i = t0; i < 2048; i += nthr) {
    int cell = (int)(i >> 10), n = (int)(i & 1023), h = n >> 2, g = n & 3, row = g*256 + h;
    float v = cell ? (in.l2_bih[row] + in.l2_bhh[row]) : (in.g2_bih[row] + in.g2_bhh[row]);
    ws[(cell ? OFF_BL2 : OFF_BG2) + n] = v;
  }
  for (size_t i = t0; i < (size_t)2*1024*512; i += nthr) {
    int which = (int)(i / (1024*512));
    int idx = (int)(i - (size_t)which*1024*512);
    int k = idx >> 9, n = idx & 511;
    const float* W = which ? in.p2_W1 : in.p1_W1;
    ws[(which ? OFF_WP2 : OFF_WP1) + idx] = W[(size_t)n*1032 + 8 + k];
  }
  for (size_t i = t0; i < (size_t)2*8*512; i += nthr) {
    int which = (int)(i / (8*512));
    int idx = (int)(i - (size_t)which*8*512);
    int k = idx >> 9, n = idx & 511;
    const float* W = which ? in.p2_W1 : in.p1_W1;
    ws[(which ? OFF_WEP2 : OFF_WEP1) + idx] = W[(size_t)n*1032 + k];
  }
  for (size_t i = t0; i < (size_t)2*512*256; i += nthr) {
    int which = (int)(i / (512*256));
    int idx = (int)(i - (size_t)which*512*256);
    int k = idx >> 8, n = idx & 255;
    const float* W = which ? in.p2_W2 : in.p1_W2;
    ws[(which ? OFF_WB2 : OFF_WB1) + idx] = W[(size_t)n*512 + k];
  }
  for (size_t i = t0; i < (size_t)256*96; i += nthr) {
    int k = (int)(i / 96), c = (int)(i - (size_t)k*96);
    float v = 0.f;
    if (c < V_) v = 0.5f*(in.gfc_W[(size_t)c*256 + k] + in.lfc_W[(size_t)c*256 + k]);
    ws[OFF_WOUT + i] = v;
  }
  for (size_t i = t0; i < 96; i += nthr)
    ws[OFF_BOUT + i] = (i < V_) ? 0.5f*(in.gfc_b[i] + in.lfc_b[i]) : 0.f;
}

// ---------------- main persistent kernel (XCD-local) ----------------
__global__ __launch_bounds__(NTHR) void k_main(InP in, float* ws, float* __restrict__ out)
{
  __shared__ __attribute__((aligned(16))) float sA[2*2176];
  __shared__ __attribute__((aligned(16))) float sW[2*4224];
  __shared__ __attribute__((aligned(16))) float sWe[8*132];
  __shared__ __attribute__((aligned(16))) float sE[512];
  // + 28KB dynamic LDS (unused) pushes total >80KB -> exactly 1 block/CU,
  // so 256 blocks <-> 256 CUs and each XCD hosts exactly 32 blocks.

  float* GH1C = ws + OFF_GH1C;  float* GC1C = ws + OFF_GC1C;
  float* GH1P = ws + OFF_GH1P;  float* GC1P = ws + OFF_GC1P;
  float* LH1  = ws + OFF_LH1;   float* LC1  = ws + OFF_LC1;
  float* GH2C = ws + OFF_GH2C;  float* GC2C = ws + OFF_GC2C;
  float* GH2P = ws + OFF_GH2P;  float* GC2P = ws + OFF_GC2P;
  float* LH2  = ws + OFF_LH2;   float* LC2  = ws + OFF_LC2;
  float* MLP1 = ws + OFF_MLP1;  float* EXB  = ws + OFF_EX;
  const float* WG1 = ws + OFF_WG1;  const float* WE1 = ws + OFF_WE1;  const float* BG1 = ws + OFF_BG1;
  const float* WL2 = ws + OFF_WL2;  const float* BL2 = ws + OFF_BL2;
  const float* WG2 = ws + OFF_WG2;  const float* BG2 = ws + OFF_BG2;
  const float* WP1 = ws + OFF_WP1;  const float* WEP1 = ws + OFF_WEP1;
  const float* WP2 = ws + OFF_WP2;  const float* WEP2 = ws + OFF_WEP2;
  const float* WB1 = ws + OFF_WB1;  const float* WB2 = ws + OFF_WB2;
  const float* WOUT = ws + OFF_WOUT; const float* BOUT = ws + OFF_BOUT;

  // ---- physical XCD id + slot within XCD ----
  unsigned xcc;
  asm volatile("s_getreg_b32 %0, hwreg(HW_REG_XCC_ID)" : "=s"(xcc));
  xcc &= 7u;
  unsigned* barx = ((unsigned*)(ws + OFF_BAR)) + xcc*1024;
  unsigned* arr  = barx;            // 32 slots * 16 uints (64B apart)
  unsigned* go   = barx + 512;
  unsigned* reg  = barx + 544;      // registration counter (one RMW per block, once)
  __shared__ unsigned s_slot;
  if (threadIdx.x == 0)
    s_slot = __hip_atomic_fetch_add(reg, 1u, __ATOMIC_RELAXED, __HIP_MEMORY_SCOPE_AGENT);
  __syncthreads();
  const int slot  = (int)(s_slot & 31u);
  const int rows0 = (int)xcc * 128;
  unsigned ep = 0;

  for (int t = 0; t < T_; ++t) {
    const int sel = t & 1;
    const float* ex = EXB + sel*(B_*8);
    float* lh1o = LH1 + sel*S_;      float* lh1n = LH1 + (sel^1)*S_;
    float* lc1o = LC1 + sel*S_;      float* lc1n = LC1 + (sel^1)*S_;
    float* lh2o = LH2 + sel*S_;      float* lh2n = LH2 + (sel^1)*S_;
    float* lc2o = LC2 + sel*S_;      float* lc2n = LC2 + (sel^1)*S_;

    // ===== S1: layer-1 gates (g1 | l1): 32 slots, tile 64x128 =====
    {
      const int rt = slot & 1, ct = slot >> 1;      // ct in [0,16)
      const int r0 = rows0 + rt*64, ct0 = ct*128;
      const int cell = ct >> 3;
      GateEpi<4> epi{ cell ? lc1o : GC1C,
                      cell ? lh1n : GH1P,
                      cell ? lc1n : GC1P,
                      BG1 + ct0, r0, (ct0 & 1023) >> 2 };
      mm_tile<128,4,1,true>(sA, sW, sWe, sE,
                            cell ? lh1o : GH1C, nullptr, nullptr, nullptr,
                            WG1, 2048, ct0, WE1, 2048, ex, r0, epi);
    }
    gbar_x(arr, go, slot, ++ep);

    // ===== S2: p1-MLP1 (slots 0-15) || l2 gates (slots 16-31) =====
    if (slot < 16) {
      const int rt = slot & 1, ct = slot >> 1;      // ct in [0,8)
      const int r0 = rows0 + rt*64, c0 = ct*64;
      MlpEpi epi{ MLP1, in.p1_b1, r0, c0 };
      mm_tile<64,2,4,true>(sA, sW, sWe, sE,
                           GH1P, GC1P, lh1n, lc1n,
                           WP1, 512, c0, WEP1, 512, ex, r0, epi);
    } else {
      const int s2 = slot - 16;
      const int rt = s2 & 1, ct = s2 >> 1;          // ct in [0,8)
      const int r0 = rows0 + rt*64, ct0 = ct*128;
      GateEpi<4> epi{ lc2o, lh2n, lc2n, BL2 + ct0, r0, ct0 >> 2 };
      mm_tile<128,4,2,false>(sA, sW, sWe, sE,
                             lh1n, lh2o, nullptr, nullptr,
                             WL2, 1024, ct0, nullptr, 0, nullptr, r0, epi);
    }
    gbar_x(arr, go, slot, ++ep);

    // ===== S3: p1 finish + mix1 (slots 0-7) || ex(t+1) (slots 8-9) =====
    if (slot < 8) {
      stage_F2(rows0 + slot*16, MLP1, WB1, in.p1_b2, in.p1_W3, in.p1_b3,
               lh1n, lc1n, GH1P, GC1P, GH1C, GC1C);
    } else if (slot < 10 && t < T_-1) {
      const int rb = rows0 + (slot-8)*64;
      const int r = rb + (threadIdx.x >> 3), j = threadIdx.x & 7;
      EXB[((t+1)&1)*(B_*8) + r*8 + j] = in.emb[(size_t)in.seq[(size_t)r*T_ + t + 1]*8 + j];
    }
    gbar_x(arr, go, slot, ++ep);

    // ===== S4: g2 gates: 32 slots, tile 64x64 =====
    {
      const int rt = slot & 1, ct = slot >> 1;      // ct in [0,16)
      const int r0 = rows0 + rt*64, ct0 = ct*64;
      GateEpi<2> epi{ GC2C, GH2P, GC2P, BG2 + ct0, r0, ct0 >> 2 };
      mm_tile<64,2,2,false>(sA, sW, sWe, sE,
                            GH1C, GH2C, nullptr, nullptr,
                            WG2, 1024, ct0, nullptr, 0, nullptr, r0, epi);
    }
    gbar_x(arr, go, slot, ++ep);

    // ===== S5: p2-MLP1 (slots 0-15) || out(t-1) (slots 16-31) =====
    if (slot < 16) {
      const int rt = slot & 1, ct = slot >> 1;
      const int r0 = rows0 + rt*64, c0 = ct*64;
      MlpEpi epi{ MLP1, in.p2_b1, r0, c0 };
      mm_tile<64,2,4,true>(sA, sW, sWe, sE,
                           GH2P, GC2P, lh2n, lc2n,
                           WP2, 512, c0, WEP2, 512, ex, r0, epi);
    } else if (t > 0) {
      stage_OUT(GH2C, WOUT, BOUT, out, rows0 + (slot-16)*8, t-1);
    }
    gbar_x(arr, go, slot, ++ep);

    // ===== S6: p2 finish + mix2 (slots 0-7) =====
    if (slot < 8) {
      stage_F2(rows0 + slot*16, MLP1, WB2, in.p2_b2, in.p2_W3, in.p2_b3,
               lh2n, lc2n, GH2P, GC2P, GH2C, GC2C);
    }
    gbar_x(arr, go, slot, ++ep);
  }

  // final output column t = 255
  if (slot >= 16) stage_OUT(GH2C, WOUT, BOUT, out, rows0 + (slot-16)*8, 255);
}

// ---------------- host ----------------
extern "C" void kernel_launch(void* const* d_in, const int* in_sizes, int n_in,
                              void* d_out, int out_size, void* d_ws, size_t ws_size,
                              hipStream_t stream)
{
  if (ws_size < WS_FLOATS * sizeof(float)) return;

  InP in;
  in.seq    = (const int*)  d_in[0];
  in.emb    = (const float*)d_in[1];
  in.g1_Wih = (const float*)d_in[2];  in.g1_Whh = (const float*)d_in[3];
  in.g1_bih = (const float*)d_in[4];  in.g1_bhh = (const float*)d_in[5];
  in.g2_Wih = (const float*)d_in[6];  in.g2_Whh = (const float*)d_in[7];
  in.g2_bih = (const float*)d_in[8];  in.g2_bhh = (const float*)d_in[9];
  in.l1_Wih = (const float*)d_in[10]; in.l1_Whh = (const float*)d_in[11];
  in.l1_bih = (const float*)d_in[12]; in.l1_bhh = (const float*)d_in[13];
  in.l2_Wih = (const float*)d_in[14]; in.l2_Whh = (const float*)d_in[15];
  in.l2_bih = (const float*)d_in[16]; in.l2_bhh = (const float*)d_in[17];
  in.p1_W1  = (const float*)d_in[18]; in.p1_b1  = (const float*)d_in[19];
  in.p1_W2  = (const float*)d_in[20]; in.p1_b2  = (const float*)d_in[21];
  in.p1_W3  = (const float*)d_in[22]; in.p1_b3  = (const float*)d_in[23];
  in.p2_W1  = (const float*)d_in[24]; in.p2_b1  = (const float*)d_in[25];
  in.p2_W2  = (const float*)d_in[26]; in.p2_b2  = (const float*)d_in[27];
  in.p2_W3  = (const float*)d_in[28]; in.p2_b3  = (const float*)d_in[29];
  in.gfc_W  = (const float*)d_in[30]; in.gfc_b  = (const float*)d_in[31];
  in.lfc_W  = (const float*)d_in[32]; in.lfc_b  = (const float*)d_in[33];

  float* ws  = (float*)d_ws;
  float* out = (float*)d_out;

  k_setup<<<256, 256, 0, stream>>>(in, ws);
  k_main <<<NBLK, NTHR, 28672, stream>>>(in, ws, out);   // 28KB dynamic LDS: occupancy pin
}